// Round 9
// baseline (148.586 us; speedup 1.0000x reference)
//
#include <hip/hip_runtime.h>

// Problem constants
#define BB     128
#define TOPK   32
#define MN     64
#define NODES  258          // MAX_NODES + 2
#define NREL   400
#define SEG1_OFF 512        // rel rows padded 400 -> 512 (x128)
#define SEG2_OFF 4608       // 512 + 4096 (ent); node rows follow
#define NROWS_TOT 37632     // 512 + 4096 + 33024  (= 294 x 128)
#define COLSPLIT 3
#define GEMM_BLOCKS ((NROWS_TOT / 128) * COLSPLIT)   // 882

typedef __bf16 bf16x8 __attribute__((ext_vector_type(8)));
typedef float  f32x4  __attribute__((ext_vector_type(4)));

__device__ inline unsigned short f2bf(float f) {
    unsigned u = __float_as_uint(f);
    u = (u + 0x7fff + ((u >> 16) & 1)) >> 16;   // round-to-nearest-even
    return (unsigned short)u;
}
__device__ inline uint4 conv8(float4 a, float4 b) {
    union { unsigned short s[8]; uint4 v; } u;
    u.s[0]=f2bf(a.x); u.s[1]=f2bf(a.y); u.s[2]=f2bf(a.z); u.s[3]=f2bf(a.w);
    u.s[4]=f2bf(b.x); u.s[5]=f2bf(b.y); u.s[6]=f2bf(b.z); u.s[7]=f2bf(b.w);
    return u.v;
}
__device__ inline float2 up2(unsigned u) {      // packed bf16 pair -> 2 floats
    float2 r;
    r.x = __uint_as_float(u << 16);
    r.y = __uint_as_float(u & 0xffff0000u);
    return r;
}
__device__ inline float fsig(float x) {
    float e = __builtin_amdgcn_exp2f(-1.442695041f * x);
    return __builtin_amdgcn_rcpf(1.f + e);
}
__device__ inline float ftanh(float x) {
    x = fminf(15.f, fmaxf(-15.f, x));
    float e = __builtin_amdgcn_exp2f(2.885390082f * x);
    return (e - 1.f) * __builtin_amdgcn_rcpf(e + 1.f);
}

// ---------------------------------------------------------------------------
// prep: build unified bf16 A matrix [rel(512) | ent-gather(4096) | node(33024)]
// (x8 vectorized) with fused node_emb -> out fp32 copy. W handled in-gemm.
__global__ __launch_bounds__(256) void prep(
        const float* __restrict__ node_emb, const float* __restrict__ ent_tab,
        const float* __restrict__ rel_tab, const int* __restrict__ aim_ent,
        unsigned short* __restrict__ A, float* __restrict__ out) {
    int gid = blockIdx.x * 256 + threadIdx.x;   // NROWS_TOT*16 threads
    int row = gid >> 4, kc = (gid & 15) << 3;
    float4 v0 = {0.f,0.f,0.f,0.f}, v1 = {0.f,0.f,0.f,0.f};
    if (row < NREL) {
        const float4* p = (const float4*)(rel_tab + (size_t)row * 128 + kc);
        v0 = p[0]; v1 = p[1];
    } else if (row < SEG1_OFF) {
        // zero pad
    } else if (row < SEG2_OFF) {
        const float* e = ent_tab + (size_t)aim_ent[row - SEG1_OFF] * 128 + kc;
        v0 = ((const float4*)e)[0]; v1 = ((const float4*)e)[1];
    } else {
        int n = row - SEG2_OFF;
        const float4* p = (const float4*)(node_emb + (size_t)n * 128 + kc);
        v0 = p[0]; v1 = p[1];
        float4* o = (float4*)(out + (size_t)n * 128 + kc);
        o[0] = v0; o[1] = v1;                   // fused copy to scatter base
    }
    *(uint4*)(A + (size_t)row * 128 + kc) = conv8(v0, v1);
}

// ---------------------------------------------------------------------------
// G = A @ W_seg^T + bias. A from packed bf16; W staged fp32->bf16 into LDS in
// MFMA-fragment lane order. All 8 col-tiles accumulate in registers; epilogue
// bounces the C-tile through per-wave LDS to emit fully-coalesced dwordx4
// stores (vs 64 scattered 2-B stores per lane).
__global__ __launch_bounds__(256) void mfma_gemm(
        const unsigned short* __restrict__ A, const float* __restrict__ W_ih,
        const float* __restrict__ W_hh, const float* __restrict__ b_ih,
        const float* __restrict__ b_hh, unsigned short* __restrict__ G) {
    __shared__ __align__(16) unsigned short Bs[128 * 128];   // 32 KB
    const int tid = threadIdx.x;
    const int w = tid >> 6, lane = tid & 63;
    const int rb = blockIdx.x / COLSPLIT, cs = blockIdx.x % COLSPLIT;
    const int brow = rb * 128;
    const int row0 = brow + w * 32;
    const int seg  = (brow < SEG1_OFF) ? 0 : (brow < SEG2_OFF ? 1 : 2);
    const int limit = (seg == 0) ? NREL : NROWS_TOT;
    const int colbase = cs * 128;

    // Stage W slice (fp32 -> bf16): chunk d = (tt*4+kbb)*64 + qq*16 + cc  <-
    // W_seg[n=colbase+tt*16+cc][k=kbb*32+qq*8 .. +7]  (reader lane-linear order)
#pragma unroll
    for (int ii = 0; ii < 8; ++ii) {
        int dst = ii * 256 + tid;              // 0..2047
        int g = dst >> 6, rem = dst & 63;
        int qq = rem >> 4, cc = rem & 15;
        int tt = g >> 2, kbb = g & 3;
        int n = colbase + tt * 16 + cc, k = kbb * 32 + qq * 8;
        const float* src = (seg == 0) ? (W_ih + n * 256 + 128 + k)
                         : (seg == 1) ? (W_ih + n * 256 + k)
                                      : (W_hh + n * 128 + k);
        float4 w0 = ((const float4*)src)[0], w1 = ((const float4*)src)[1];
        *(uint4*)(Bs + dst * 8) = conv8(w0, w1);
    }

    const int q = lane >> 4, c = lane & 15;
    const int koff = q << 3;
    bf16x8 a0[4], a1[4];
    {
        const unsigned short* Ar0 = A + (size_t)(row0 + c) * 128 + koff;
        const unsigned short* Ar1 = Ar0 + 16 * 128;
#pragma unroll
        for (int kb = 0; kb < 4; ++kb) {
            a0[kb] = *(const bf16x8*)(Ar0 + kb * 32);
            a1[kb] = *(const bf16x8*)(Ar1 + kb * 32);
        }
    }
    float bv[8];
#pragma unroll
    for (int t = 0; t < 8; ++t) {
        int gc = colbase + t * 16 + c;
        bv[t] = (seg == 0) ? 0.f : (seg == 1 ? b_ih[gc] : b_hh[gc]);
    }

    __syncthreads();

    // MFMA loop: pure ds_read + MFMA, all 16 accumulators held in registers
    f32x4 ACC0[8], ACC1[8];
#pragma unroll
    for (int t = 0; t < 8; ++t) {
        bf16x8 bf[4];
#pragma unroll
        for (int kb = 0; kb < 4; ++kb)
            bf[kb] = *(const bf16x8*)(Bs + (size_t)((t * 4 + kb) * 64 + lane) * 8);
        f32x4 acc0 = {0.f,0.f,0.f,0.f}, acc1 = {0.f,0.f,0.f,0.f};
#pragma unroll
        for (int kb = 0; kb < 4; ++kb) {
            acc0 = __builtin_amdgcn_mfma_f32_16x16x32_bf16(a0[kb], bf[kb], acc0, 0, 0, 0);
            acc1 = __builtin_amdgcn_mfma_f32_16x16x32_bf16(a1[kb], bf[kb], acc1, 0, 0, 0);
        }
        ACC0[t] = acc0; ACC1[t] = acc1;
    }

    // Epilogue: per-wave LDS bounce (wave-private 8 KB region of Bs) ->
    // coalesced uint4 stores (4 full 128-B lines per instruction).
    __syncthreads();                           // all Bs reads done
    unsigned short* Cs = Bs + w * 4096;        // 32 rows x 128 cols bf16
#pragma unroll
    for (int t = 0; t < 8; ++t) {
#pragma unroll
        for (int i2 = 0; i2 < 4; ++i2) {
            Cs[(q * 4 + i2) * 128 + t * 16 + c]        = f2bf(ACC0[t][i2] + bv[t]);
            Cs[(q * 4 + i2 + 16) * 128 + t * 16 + c]   = f2bf(ACC1[t][i2] + bv[t]);
        }
    }
    // wave-private region: no barrier needed (compiler waits lgkmcnt)
#pragma unroll
    for (int ii = 0; ii < 8; ++ii) {
        int f = ii * 64 + lane;                // 0..511 uint4 chunks
        int row = f >> 4;                      // 0..31 local row
        int colb = (f & 15) * 8;               // 0..120
        int grow = row0 + row;
        if (grow < limit)
            *(uint4*)(G + (size_t)grow * 384 + colbase + colb) =
                *(const uint4*)(Cs + row * 128 + colb);
    }
}

// ---------------------------------------------------------------------------
// GRU gates + masked mean + last-wins scatter. Block = 512 threads per (b,t):
// 8 m-groups (serial depth <= 8) x 64 lanes (packed bf16 h-pairs).
// XCD-aware mapping: all 32 t-blocks of a batch b share idx%8 -> same XCD.
__global__ __launch_bounds__(512) void gru_agg(
        const unsigned short* __restrict__ A, const unsigned short* __restrict__ G,
        const int* __restrict__ aim_nodes, const int* __restrict__ neighbors,
        const int* __restrict__ nb_num, float* __restrict__ out) {
    const int idx = blockIdx.x;
    const int xcd = idx & 7, slot = idx >> 3;
    const int b = (slot >> 5) * 8 + xcd;       // 16 b's per XCD
    const int t = slot & 31;
    const int bt = b * TOPK + t;
    const int tid = threadIdx.x;
    const int w = tid >> 6, lane = tid & 63;   // w = m-group, lane = h-pair

    // numpy fancy-assign: last duplicate wins (uniform across block)
    const int myaim = aim_nodes[bt];
    for (int t2 = t + 1; t2 < TOPK; ++t2)
        if (aim_nodes[b * TOPK + t2] == myaim) return;

    __shared__ float2 part[8][64];

    int num = nb_num[bt];
    num = (num < 0) ? 0 : (num > MN ? MN : num);

    const unsigned short* Gl = G + 2 * lane;   // lane's h-pair column offset
    const unsigned short* Ge = Gl + (size_t)(SEG1_OFF + bt) * 384;
    const float2 ge_r = up2(*(const unsigned*)(Ge));
    const float2 ge_z = up2(*(const unsigned*)(Ge + 128));
    const float2 ge_n = up2(*(const unsigned*)(Ge + 256));

    const unsigned short* Gh = Gl + ((size_t)SEG2_OFF + (size_t)b * NODES) * 384;
    const unsigned short* Av = A + ((size_t)SEG2_OFF + (size_t)b * NODES) * 128 + 2 * lane;
    const int2* nbp = (const int2*)neighbors + (size_t)bt * MN;

    float2 acc = {0.f, 0.f};
    for (int m = w; m < num; m += 8) {
        int2 p = nbp[m];                       // wave-uniform -> s_load
        const unsigned short* gr = Gl + (size_t)p.y * 384;
        const unsigned short* gh = Gh + (size_t)p.x * 384;
        unsigned ur0 = *(const unsigned*)(gr);
        unsigned ur1 = *(const unsigned*)(gr + 128);
        unsigned ur2 = *(const unsigned*)(gr + 256);
        unsigned uh0 = *(const unsigned*)(gh);
        unsigned uh1 = *(const unsigned*)(gh + 128);
        unsigned uh2 = *(const unsigned*)(gh + 256);
        unsigned uv  = *(const unsigned*)(Av + (size_t)p.x * 128);
        float2 r0 = up2(ur0), r1 = up2(ur1), r2 = up2(ur2);
        float2 h0 = up2(uh0), h1 = up2(uh1), h2 = up2(uh2);
        float2 hv = up2(uv);
        float rx = fsig(ge_r.x + r0.x + h0.x);
        float zx = fsig(ge_z.x + r1.x + h1.x);
        float nx = ftanh(ge_n.x + r2.x + rx * h2.x);
        acc.x += (1.f - zx) * nx + zx * hv.x;
        float ry = fsig(ge_r.y + r0.y + h0.y);
        float zy = fsig(ge_z.y + r1.y + h1.y);
        float ny = ftanh(ge_n.y + r2.y + ry * h2.y);
        acc.y += (1.f - zy) * ny + zy * hv.y;
    }
    part[w][lane] = acc;
    __syncthreads();
    if (tid < 64) {
        float2 s = part[0][lane];
#pragma unroll
        for (int k = 1; k < 8; ++k) { s.x += part[k][lane].x; s.y += part[k][lane].y; }
        const float denom = (num > 0) ? (float)num : 1.f;
        const float sc = __builtin_amdgcn_rcpf(denom);
        float2 r; r.x = s.x * sc; r.y = s.y * sc;
        *(float2*)(out + ((size_t)b * NODES + myaim) * 128 + 2 * lane) = r;
    }
}

// ---------------------------------------------------------------------------
extern "C" void kernel_launch(void* const* d_in, const int* in_sizes, int n_in,
                              void* d_out, int out_size, void* d_ws, size_t ws_size,
                              hipStream_t stream) {
    const float* node_emb = (const float*)d_in[0];
    const float* ent_tab  = (const float*)d_in[1];
    const float* rel_tab  = (const float*)d_in[2];
    const float* W_ih     = (const float*)d_in[3];
    const float* W_hh     = (const float*)d_in[4];
    const float* b_ih     = (const float*)d_in[5];
    const float* b_hh     = (const float*)d_in[6];
    const int* aim_nodes  = (const int*)d_in[7];
    const int* aim_ent    = (const int*)d_in[8];
    const int* neighbors  = (const int*)d_in[9];
    const int* nb_num     = (const int*)d_in[10];
    float* out = (float*)d_out;

    // ws: G bf16 28.9 MB | A bf16 9.63 MB
    unsigned short* G = (unsigned short*)d_ws;
    unsigned short* A = G + (size_t)NROWS_TOT * 384;

    hipLaunchKernelGGL(prep, dim3(NROWS_TOT * 16 / 256), dim3(256), 0, stream,
                       node_emb, ent_tab, rel_tab, aim_ent, A, out);
    hipLaunchKernelGGL(mfma_gemm, dim3(GEMM_BLOCKS), dim3(256), 0, stream,
                       A, W_ih, W_hh, b_ih, b_hh, G);
    hipLaunchKernelGGL(gru_agg, dim3(BB * TOPK), dim3(512), 0, stream,
                       A, G, aim_nodes, neighbors, nb_num, out);
}

// Round 11
// 145.928 us; speedup vs baseline: 1.0182x; 1.0182x over previous
//
#include <hip/hip_runtime.h>

// Problem constants
#define BB     128
#define TOPK   32
#define MN     64
#define NODES  258          // MAX_NODES + 2
#define NREL   400
#define SEG1_OFF 512        // rel rows padded 400 -> 512 (x128)
#define SEG2_OFF 4608       // 512 + 4096 (ent); node rows follow
#define NROWS_TOT 37632     // 512 + 4096 + 33024  (= 294 x 128 exactly)
#define COLSPLIT 3

typedef __bf16 bf16x8 __attribute__((ext_vector_type(8)));
typedef float  f32x4  __attribute__((ext_vector_type(4)));

__device__ inline unsigned short f2bf(float f) {
    unsigned u = __float_as_uint(f);
    u = (u + 0x7fff + ((u >> 16) & 1)) >> 16;   // round-to-nearest-even
    return (unsigned short)u;
}
__device__ inline float2 up2(unsigned u) {      // packed bf16 pair -> 2 floats
    float2 r;
    r.x = __uint_as_float(u << 16);
    r.y = __uint_as_float(u & 0xffff0000u);
    return r;
}
__device__ inline float fsig(float x) {
    float e = __builtin_amdgcn_exp2f(-1.442695041f * x);
    return __builtin_amdgcn_rcpf(1.f + e);
}
__device__ inline float ftanh(float x) {
    x = fminf(15.f, fmaxf(-15.f, x));
    float e = __builtin_amdgcn_exp2f(2.885390082f * x);
    return (e - 1.f) * __builtin_amdgcn_rcpf(e + 1.f);
}

// ---------------------------------------------------------------------------
// prep: region A = build unified bf16 A matrix [rel(512) | ent(4096) | node(33024)]
// (x8 vectorized, fused node_emb -> out fp32 copy); region B = pack weights + bias.
#define REGA_BLOCKS (NROWS_TOT * 16 / 256)     // 2352
#define REGB_BLOCKS (147456 / 8 / 256)         // 72
__global__ __launch_bounds__(256) void prep(
        const float* __restrict__ node_emb, const float* __restrict__ ent_tab,
        const float* __restrict__ rel_tab, const int* __restrict__ aim_ent,
        const float* __restrict__ W_ih, const float* __restrict__ W_hh,
        const float* __restrict__ b_ih, const float* __restrict__ b_hh,
        unsigned short* __restrict__ A, unsigned short* __restrict__ Wpack,
        float* __restrict__ biasb, float* __restrict__ out) {
    int gid = blockIdx.x * 256 + threadIdx.x;
    if (blockIdx.x < REGA_BLOCKS) {
        int row = gid >> 4, kc = (gid & 15) << 3;
        float4 v0 = {0.f,0.f,0.f,0.f}, v1 = {0.f,0.f,0.f,0.f};
        if (row < NREL) {
            const float4* p = (const float4*)(rel_tab + (size_t)row * 128 + kc);
            v0 = p[0]; v1 = p[1];
        } else if (row < SEG1_OFF) {
            // zero pad
        } else if (row < SEG2_OFF) {
            const float* e = ent_tab + (size_t)aim_ent[row - SEG1_OFF] * 128 + kc;
            v0 = ((const float4*)e)[0]; v1 = ((const float4*)e)[1];
        } else {
            int n = row - SEG2_OFF;
            const float4* p = (const float4*)(node_emb + (size_t)n * 128 + kc);
            v0 = p[0]; v1 = p[1];
            float4* o = (float4*)(out + (size_t)n * 128 + kc);
            o[0] = v0; o[1] = v1;               // fused copy to scatter base
        }
        union { unsigned short s[8]; uint4 v; } u;
        u.s[0]=f2bf(v0.x); u.s[1]=f2bf(v0.y); u.s[2]=f2bf(v0.z); u.s[3]=f2bf(v0.w);
        u.s[4]=f2bf(v1.x); u.s[5]=f2bf(v1.y); u.s[6]=f2bf(v1.z); u.s[7]=f2bf(v1.w);
        *(uint4*)(A + (size_t)row * 128 + kc) = u.v;
    } else {
        int rb = gid - REGA_BLOCKS * 256;      // 0..18431, 8 elems each
        int e0 = rb * 8;
        int s = e0 / 49152, r = e0 % 49152;
        int n = r >> 7, k = r & 127;
        const float* src = (s == 0) ? (W_ih + n * 256 + 128 + k)
                         : (s == 1) ? (W_ih + n * 256 + k)
                                    : (W_hh + n * 128 + k);
        float4 v0 = ((const float4*)src)[0], v1 = ((const float4*)src)[1];
        union { unsigned short s[8]; uint4 v; } u;
        u.s[0]=f2bf(v0.x); u.s[1]=f2bf(v0.y); u.s[2]=f2bf(v0.z); u.s[3]=f2bf(v0.w);
        u.s[4]=f2bf(v1.x); u.s[5]=f2bf(v1.y); u.s[6]=f2bf(v1.z); u.s[7]=f2bf(v1.w);
        *(uint4*)(Wpack + e0) = u.v;
        if (rb < 144) {                        // 1152 bias entries, 8 each
            for (int j = 0; j < 8; ++j) {
                int e = rb * 8 + j;
                int s2 = e / 384, g = e % 384;
                biasb[e] = (s2 == 0) ? 0.f : (s2 == 1 ? b_ih[g] : b_hh[g]);
            }
        }
    }
}

// ---------------------------------------------------------------------------
// G = A @ Wt_seg + bias over ALL 37632 rows (seg boundaries 128-aligned ->
// every 128-row block is seg-uniform). W-slice staged once in LDS in
// frag-lane order; zero global loads in the MFMA loop.
__global__ __launch_bounds__(256) void mfma_gemm(
        const unsigned short* __restrict__ A, const unsigned short* __restrict__ Wpack,
        const float* __restrict__ biasb, unsigned short* __restrict__ G) {
    __shared__ __align__(16) unsigned short Bs[128 * 128];   // 32 KB
    const int tid = threadIdx.x;
    const int w = tid >> 6, lane = tid & 63;
    const int rb = blockIdx.x / COLSPLIT, cs = blockIdx.x % COLSPLIT;
    const int brow = rb * 128;
    const int row0 = brow + w * 32;
    const int seg  = (brow < SEG1_OFF) ? 0 : (brow < SEG2_OFF ? 1 : 2);
    const int limit = (seg == 0) ? NREL : NROWS_TOT;
    const int colbase = cs * 128;
    const unsigned short* Wt = Wpack + (size_t)seg * 49152 + (size_t)colbase * 128;

#pragma unroll
    for (int ii = 0; ii < 8; ++ii) {
        int dst = ii * 256 + tid;
        int g = dst >> 6, rem = dst & 63;
        int qq = rem >> 4, cc = rem & 15;
        int tt = g >> 2, kbb = g & 3;
        uint4 v = *(const uint4*)(Wt + (size_t)(tt * 16 + cc) * 128 + kbb * 32 + qq * 8);
        *(uint4*)(Bs + dst * 8) = v;
    }

    const int q = lane >> 4, c = lane & 15;
    const int koff = q << 3;
    bf16x8 a0[4], a1[4];
    {
        const unsigned short* Ar0 = A + (size_t)(row0 + c) * 128 + koff;
        const unsigned short* Ar1 = Ar0 + 16 * 128;
#pragma unroll
        for (int kb = 0; kb < 4; ++kb) {
            a0[kb] = *(const bf16x8*)(Ar0 + kb * 32);
            a1[kb] = *(const bf16x8*)(Ar1 + kb * 32);
        }
    }
    float bv[8];
#pragma unroll
    for (int t = 0; t < 8; ++t)
        bv[t] = biasb[seg * 384 + colbase + t * 16 + c];

    __syncthreads();

    const int r0 = row0 + q * 4, r1 = r0 + 16;
#pragma unroll 2
    for (int t = 0; t < 8; ++t) {
        bf16x8 bf[4];
#pragma unroll
        for (int kb = 0; kb < 4; ++kb)
            bf[kb] = *(const bf16x8*)(Bs + (size_t)((t * 4 + kb) * 64 + lane) * 8);
        f32x4 acc0 = {0.f,0.f,0.f,0.f}, acc1 = {0.f,0.f,0.f,0.f};
#pragma unroll
        for (int kb = 0; kb < 4; ++kb) {
            acc0 = __builtin_amdgcn_mfma_f32_16x16x32_bf16(a0[kb], bf[kb], acc0, 0, 0, 0);
            acc1 = __builtin_amdgcn_mfma_f32_16x16x32_bf16(a1[kb], bf[kb], acc1, 0, 0, 0);
        }
        const int gc = colbase + t * 16 + c;
#pragma unroll
        for (int i2 = 0; i2 < 4; ++i2) {
            if (r0 + i2 < limit) G[(size_t)(r0 + i2) * 384 + gc] = f2bf(acc0[i2] + bv[t]);
            if (r1 + i2 < limit) G[(size_t)(r1 + i2) * 384 + gc] = f2bf(acc1[i2] + bv[t]);
        }
    }
}

// ---------------------------------------------------------------------------
// GRU gates + masked mean + last-wins scatter. Block = 512 threads per (b,t):
// 8 m-groups (one wave each, serial depth <= 8) x 64 lanes, each lane a
// packed h-pair (uint bf16x2 loads). LDS float2 reduction at the end.
// HARDENED: no early return — every block runs the identical barrier
// sequence; the last-duplicate-wins rule predicates only the final store.
__global__ __launch_bounds__(512) void gru_agg(
        const unsigned short* __restrict__ A, const unsigned short* __restrict__ G,
        const int* __restrict__ aim_nodes, const int* __restrict__ neighbors,
        const int* __restrict__ nb_num, float* __restrict__ out) {
    const int bt = blockIdx.x;
    const int b = bt >> 5, t = bt & 31;
    const int tid = threadIdx.x;
    const int w = tid >> 6, lane = tid & 63;   // w = m-group, lane = h-pair

    // numpy fancy-assign: last duplicate wins — predicate, not early exit
    const int myaim = aim_nodes[bt];
    bool wr = true;
    for (int t2 = t + 1; t2 < TOPK; ++t2)
        if (aim_nodes[b * TOPK + t2] == myaim) wr = false;

    __shared__ int2 nbs[MN];
    __shared__ float2 part[8][64];
    if (tid < MN) nbs[tid] = ((const int2*)neighbors)[(size_t)bt * MN + tid];
    __syncthreads();

    int num = nb_num[bt];
    num = (num < 0) ? 0 : (num > MN ? MN : num);

    const unsigned short* Gl = G + 2 * lane;   // lane's h-pair column offset
    const unsigned short* Ge = Gl + (size_t)(SEG1_OFF + bt) * 384;
    const float2 ge_r = up2(*(const unsigned*)(Ge));
    const float2 ge_z = up2(*(const unsigned*)(Ge + 128));
    const float2 ge_n = up2(*(const unsigned*)(Ge + 256));

    const unsigned short* Gh = Gl + ((size_t)SEG2_OFF + (size_t)b * NODES) * 384;
    const unsigned short* Av = A + ((size_t)SEG2_OFF + (size_t)b * NODES) * 128 + 2 * lane;

    float2 acc = {0.f, 0.f};
    for (int m = w; m < num; m += 8) {
        int2 p = nbs[m];
        const unsigned short* gr = Gl + (size_t)p.y * 384;
        const unsigned short* gh = Gh + (size_t)p.x * 384;
        unsigned ur0 = *(const unsigned*)(gr);
        unsigned ur1 = *(const unsigned*)(gr + 128);
        unsigned ur2 = *(const unsigned*)(gr + 256);
        unsigned uh0 = *(const unsigned*)(gh);
        unsigned uh1 = *(const unsigned*)(gh + 128);
        unsigned uh2 = *(const unsigned*)(gh + 256);
        unsigned uv  = *(const unsigned*)(Av + (size_t)p.x * 128);
        float2 r0 = up2(ur0), r1 = up2(ur1), r2 = up2(ur2);
        float2 h0 = up2(uh0), h1 = up2(uh1), h2 = up2(uh2);
        float2 hv = up2(uv);
        float rx = fsig(ge_r.x + r0.x + h0.x);
        float zx = fsig(ge_z.x + r1.x + h1.x);
        float nx = ftanh(ge_n.x + r2.x + rx * h2.x);
        acc.x += (1.f - zx) * nx + zx * hv.x;
        float ry = fsig(ge_r.y + r0.y + h0.y);
        float zy = fsig(ge_z.y + r1.y + h1.y);
        float ny = ftanh(ge_n.y + r2.y + ry * h2.y);
        acc.y += (1.f - zy) * ny + zy * hv.y;
    }
    part[w][lane] = acc;
    __syncthreads();
    if (wr && tid < 64) {
        float2 s = part[0][lane];
#pragma unroll
        for (int k = 1; k < 8; ++k) { s.x += part[k][lane].x; s.y += part[k][lane].y; }
        const float denom = (num > 0) ? (float)num : 1.f;
        const float sc = __builtin_amdgcn_rcpf(denom);
        float2 r; r.x = s.x * sc; r.y = s.y * sc;
        *(float2*)(out + ((size_t)b * NODES + myaim) * 128 + 2 * lane) = r;
    }
}

// ---------------------------------------------------------------------------
extern "C" void kernel_launch(void* const* d_in, const int* in_sizes, int n_in,
                              void* d_out, int out_size, void* d_ws, size_t ws_size,
                              hipStream_t stream) {
    const float* node_emb = (const float*)d_in[0];
    const float* ent_tab  = (const float*)d_in[1];
    const float* rel_tab  = (const float*)d_in[2];
    const float* W_ih     = (const float*)d_in[3];
    const float* W_hh     = (const float*)d_in[4];
    const float* b_ih     = (const float*)d_in[5];
    const float* b_hh     = (const float*)d_in[6];
    const int* aim_nodes  = (const int*)d_in[7];
    const int* aim_ent    = (const int*)d_in[8];
    const int* neighbors  = (const int*)d_in[9];
    const int* nb_num     = (const int*)d_in[10];
    float* out = (float*)d_out;

    // ws: G bf16 28.9 MB | A bf16 9.63 MB | Wpack 288 KB | biasb ~4.6 KB
    unsigned short* G     = (unsigned short*)d_ws;
    unsigned short* A     = G + (size_t)NROWS_TOT * 384;
    unsigned short* Wpack = A + (size_t)NROWS_TOT * 128;
    float*          biasb = (float*)(Wpack + 3 * 384 * 128);

    hipLaunchKernelGGL(prep, dim3(REGA_BLOCKS + REGB_BLOCKS), dim3(256), 0, stream,
                       node_emb, ent_tab, rel_tab, aim_ent, W_ih, W_hh, b_ih, b_hh,
                       A, Wpack, biasb, out);
    hipLaunchKernelGGL(mfma_gemm, dim3((NROWS_TOT / 128) * COLSPLIT), dim3(256), 0, stream,
                       A, Wpack, biasb, G);
    hipLaunchKernelGGL(gru_agg, dim3(BB * TOPK), dim3(512), 0, stream,
                       A, G, aim_nodes, neighbors, nb_num, out);
}